// Round 12
// baseline (8580.919 us; speedup 1.0000x reference)
//
#include <hip/hip_runtime.h>

// ---------------------------------------------------------------------------
// SelfAttention (QKV -> softmax(QK^T/sqrt(D)) V) -> LSTM(1024 steps)
// B=16, S=1024, D=H=2048.  All heavy math in bf16 MFMA, fp32 accumulate.
// ---------------------------------------------------------------------------

typedef unsigned short u16;
typedef unsigned int u32;
typedef unsigned long long u64;
typedef __attribute__((ext_vector_type(8))) __bf16 bf16x8;
typedef __attribute__((ext_vector_type(8))) unsigned short u16x8;
typedef __attribute__((ext_vector_type(4))) float f32x4;
typedef __attribute__((ext_vector_type(4))) unsigned int u32x4;

#define DEV static __device__ __forceinline__

DEV u16 f2bf(float f) {  // RTNE float->bf16 (finite inputs)
  union { float f; unsigned u; } x; x.f = f;
  return (u16)((x.u + 0x7FFFu + ((x.u >> 16) & 1u)) >> 16);
}
DEV float bf2f(u16 h) {
  union { unsigned u; float f; } x; x.u = (unsigned)h << 16;
  return x.f;
}
DEV void gload_lds16(const void* g, void* l) {
  __builtin_amdgcn_global_load_lds(
      (const __attribute__((address_space(1))) unsigned int*)g,
      (__attribute__((address_space(3))) unsigned int*)l, 16, 0, 0);
}

// -------------------------- fp32 -> bf16 convert ---------------------------
__global__ __launch_bounds__(256) void k_cvt(const float* __restrict__ in,
                                             u16* __restrict__ out, long n) {
  long i = (((long)blockIdx.x << 8) | threadIdx.x) << 3;
  if (i >= n) return;
  float4 f0 = *(const float4*)(in + i);
  float4 f1 = *(const float4*)(in + i + 4);
  u16x8 p;
  p[0] = f2bf(f0.x); p[1] = f2bf(f0.y); p[2] = f2bf(f0.z); p[3] = f2bf(f0.w);
  p[4] = f2bf(f1.x); p[5] = f2bf(f1.y); p[6] = f2bf(f1.z); p[7] = f2bf(f1.w);
  *(u16x8*)(out + i) = p;
}

__global__ __launch_bounds__(256) void k_addb(const float* __restrict__ a,
                                              const float* __restrict__ b,
                                              float* __restrict__ o, int n) {
  int i = blockIdx.x * 256 + threadIdx.x;
  if (i < n) o[i] = a[i] + b[i];
}

// ------------------------------- NT GEMM -----------------------------------
// C[m,n] = scale * sum_k A[m,k]*B[n,k] + bias[n].  A:[M,K] B:[N,K] row-major,
// lda=ldb=K, ldc=N.  128x128 tile, 4 waves, BK=32, 16x16x32 bf16 MFMA,
// global_load_lds(16B) staging (m97 structure) + bijective XCD swizzle.
template<int OBF>
__global__ __launch_bounds__(256) void k_gemm_nt(
    const u16* __restrict__ A, const u16* __restrict__ B, void* __restrict__ Cv,
    const float* __restrict__ bias, float scale, int M, int N, int K,
    long sA, long sB, long sC) {
  __shared__ __attribute__((aligned(16))) u16 As[4096];  // [128][32]
  __shared__ __attribute__((aligned(16))) u16 Bs[4096];
  const int tid = threadIdx.x;
  const int lane = tid & 63;
  const int wm = ((tid >> 7) & 1) * 64;   // wave row
  const int wn = ((tid >> 6) & 1) * 64;   // wave col
  // XCD-aware swizzle (bijective; all grids here have nwg % 8 == 0)
  const int gx = gridDim.x;
  int lin = blockIdx.y * gx + blockIdx.x;
  const int nwg = gx * gridDim.y;
  if ((nwg & 7) == 0) lin = (lin & 7) * (nwg >> 3) + (lin >> 3);
  const long bm = (long)(lin / gx) << 7;
  const long bn = (long)(lin % gx) << 7;
  const u16* Ab = A + (long)blockIdx.z * sA;
  const u16* Bb = B + (long)blockIdx.z * sB;
  const int srow = tid >> 2, scol = (tid & 3) << 3;
  const u16* ga0 = Ab + (bm + srow) * (long)K + scol;
  const u16* gb0 = Bb + (bn + srow) * (long)K + scol;
  const long k64 = (long)K << 6;          // 64 rows worth of elements
  char* lA = (char*)As + tid * 16;        // lane0 of wave w -> wave base
  char* lB = (char*)Bs + tid * 16;
  f32x4 acc[4][4] = {};
  const int fr = lane & 15, fk = (lane >> 4) << 3;
  for (int kt = 0; kt < K; kt += 32) {
    gload_lds16(ga0 + kt, lA);
    gload_lds16(ga0 + k64 + kt, lA + 4096);
    gload_lds16(gb0 + kt, lB);
    gload_lds16(gb0 + k64 + kt, lB + 4096);
    __syncthreads();                      // drains vmcnt before barrier
    bf16x8 av[4], bv[4];
#pragma unroll
    for (int x = 0; x < 4; ++x) {
      av[x] = *(const bf16x8*)&As[(wm + x * 16 + fr) * 32 + fk];
      bv[x] = *(const bf16x8*)&Bs[(wn + x * 16 + fr) * 32 + fk];
    }
#pragma unroll
    for (int i = 0; i < 4; ++i)
#pragma unroll
      for (int j = 0; j < 4; ++j)
        acc[i][j] = __builtin_amdgcn_mfma_f32_16x16x32_bf16(av[i], bv[j], acc[i][j], 0, 0, 0);
    __syncthreads();
  }
  const long cb = (long)blockIdx.z * sC;
#pragma unroll
  for (int j = 0; j < 4; ++j) {
    const long col = bn + wn + j * 16 + fr;
    const float bb = bias ? bias[col] : 0.f;
#pragma unroll
    for (int i = 0; i < 4; ++i) {
      const long r0 = bm + wm + i * 16 + ((lane >> 4) << 2);
#pragma unroll
      for (int r = 0; r < 4; ++r) {
        const float v = acc[i][j][r] * scale + bb;   // C/D: col=lane&15, row=(lane>>4)*4+r
        const long off = cb + (r0 + r) * (long)N + col;
        if (OBF) ((u16*)Cv)[off] = f2bf(v);
        else     ((float*)Cv)[off] = v;
      }
    }
  }
}

// ------------------------------ row softmax --------------------------------
__global__ __launch_bounds__(256) void k_softmax(const float* __restrict__ S,
                                                 u16* __restrict__ P) {
  __shared__ float red[8];
  const long row = blockIdx.x;
  const float* sr = S + (row << 10);
  const int t = threadIdx.x, lane = t & 63, w = t >> 6;
  float v0 = sr[t], v1 = sr[t + 256], v2 = sr[t + 512], v3 = sr[t + 768];
  float m = fmaxf(fmaxf(v0, v1), fmaxf(v2, v3));
#pragma unroll
  for (int o = 32; o; o >>= 1) m = fmaxf(m, __shfl_xor(m, o));
  if (lane == 0) red[w] = m;
  __syncthreads();
  m = fmaxf(fmaxf(red[0], red[1]), fmaxf(red[2], red[3]));
  v0 = __expf(v0 - m); v1 = __expf(v1 - m); v2 = __expf(v2 - m); v3 = __expf(v3 - m);
  float s = v0 + v1 + v2 + v3;
#pragma unroll
  for (int o = 32; o; o >>= 1) s += __shfl_xor(s, o);
  if (lane == 0) red[4 + w] = s;
  __syncthreads();
  s = red[4] + red[5] + red[6] + red[7];
  const float rs = 1.f / s;
  u16* pr = P + (row << 10);
  pr[t] = f2bf(v0 * rs); pr[t + 256] = f2bf(v1 * rs);
  pr[t + 512] = f2bf(v2 * rs); pr[t + 768] = f2bf(v3 * rs);
}

// ------------------------- V transpose (per batch) -------------------------
__global__ __launch_bounds__(256) void k_transpose(const u16* __restrict__ V,
                                                   u16* __restrict__ VT) {
  __shared__ __attribute__((aligned(16))) u16 tile[64][80];
  const long b = blockIdx.z;
  const long t0 = (long)blockIdx.y << 6, d0 = (long)blockIdx.x << 6;
  const int r = threadIdx.x >> 3, c8 = (threadIdx.x & 7) << 3;
  const u16* src = V + ((b << 10) + t0) * 2048 + d0;
#pragma unroll
  for (int p = 0; p < 2; ++p) {
    const int rr = r + p * 32;
    *(u16x8*)&tile[rr][c8] = *(const u16x8*)(src + (long)rr * 2048 + c8);
  }
  __syncthreads();
  u16* dst = VT + ((b << 11) + d0) * 1024 + t0;
#pragma unroll
  for (int p = 0; p < 2; ++p) {
    const int dr = r + p * 32;
    u16x8 pk;
#pragma unroll
    for (int q = 0; q < 8; ++q) pk[q] = tile[c8 + q][dr];
    *(u16x8*)(dst + (long)dr * 1024 + c8) = pk;
  }
}

// ------------------------------ LSTM recurrence ----------------------------
// Persistent kernel: 128 blocks x 256 threads (1 block/CU).  Block owns 16
// h-columns.  W_hh: gates 0,1 in XOR-swizzled LDS; gates 2,3 as fragments.
//
// TAGGED-DATA protocol (round-8 correctness + congestion fixes):
//   hbuf = u32[2][128 blk][16 batch][16 col], word = (bf16 h)<<16 | (t+1).
//   publish : each thread stores ONE coalesced tagged u32 (relaxed agent,
//             write-through).  NO drain, NO flags, NO release hop.
//   consume : bulk-load 32 dwordx4 (block-major; 8 addr bases * imm offsets
//             {0,16,2048,2064} — global imm offset is 13-bit signed),
//             check embedded tags == t; STALE-ONLY exec-masked reloads with
//             s_sleep backoff (fixes R8's whole-vector retry collapse).
//   barriers: raw lgkmcnt(0)+s_barrier (LDS-only) so publish stores stay
//             in flight across the barrier (no implicit vmcnt(0) drain).
// Safety: Z's tag-(t+1) publish implies Z finished reading slot par^1; any
// t+2 overwrite of slot par^1 requires ALL 128 tags == t+1, impossible while
// any consumer still retries step t -> observed tags in {t-2, t}; equality
// check sound.  Liveness by induction.
DEV bf16x8 wread(const char* wlds, int nrow, int k) {
  int byte = (nrow << 12) + (k << 1);
  byte ^= (nrow & 7) << 4;
  return *(const bf16x8*)(wlds + byte);
}
DEV float sigm(float x) { return 1.f / (1.f + __expf(-x)); }
DEV float tanh_fast(float x) { return 1.f - 2.f / (1.f + __expf(2.f * x)); }

__global__ __launch_bounds__(256, 1) void k_lstm(
    const u16* __restrict__ xg, const u16* __restrict__ whh,
    u32* __restrict__ hbuf, float* __restrict__ out) {
  extern __shared__ char smem[];
  char* wlds = smem;                       // 32 x 2048 bf16 = 131072 B (gates 0,1)
  float* red = (float*)(smem + 131072);    // [4 waves][16 batch x 64 gcol] = 16 KB
  const int tid = threadIdx.x, lane = tid & 63, wave = tid >> 6;
  const int j0 = blockIdx.x << 4;          // 16 columns per block
  const int am = lane & 15, ak = (lane >> 4) << 3;
  const int bb = tid >> 4, jj = tid & 15;  // gate-stage cell (all 256 threads)

  // stage W_hh gates 0,1 -> lds row = gate*16 + col (swizzled, proven layout)
  for (int it = 0; it < 32; ++it) {
    const long grow = ((long)(it >> 4) << 11) + j0 + (it & 15);
    const u16* src = whh + grow * 2048 + (tid << 3);
    int byte = (it << 12) + (tid << 4);
    byte ^= (it & 7) << 4;
    *(bf16x8*)(wlds + byte) = *(const bf16x8*)src;
  }
  // W_hh gates 2,3 fragments (compiler streams from L1/L2; proven)
  bf16x8 wf[2][16];
#pragma unroll
  for (int g2 = 0; g2 < 2; ++g2)
#pragma unroll
    for (int ks = 0; ks < 16; ++ks)
      wf[g2][ks] = *(const bf16x8*)(whh + ((long)((2 + g2) << 11) + j0 + am) * 2048 +
                                    (wave << 9) + (ks << 5) + ak);
  __syncthreads();

  float c = 0.f;
  u16 xv[4];  // this step's xg gate values (prefetched one step ahead)
#pragma unroll
  for (int g = 0; g < 4; ++g)
    xv[g] = xg[((long)bb << 10) * 8192 + (g << 11) + j0 + jj];

  // per-lane byte offset within a slot: blk = wave*32 + ks*2 + (ak>>4),
  // addr = blk*1024 + am*64 + (ak&8)*4; ks pair stride = 4096 B (base i).
  const u32 voff0 = ((u32)wave << 15) + (((u32)ak >> 4) << 10) +
                    ((u32)am << 6) + (((u32)ak & 8u) << 2);

  for (int t = 0; t < 1024; ++t) {
    const int par = t & 1;
    const u32* hslot = hbuf + ((par ^ 1) << 15);  // 131072 B per slot
    const u32 b0_ = voff0,          b1_ = voff0 + 4096,
              b2_ = voff0 + 8192,   b3_ = voff0 + 12288,
              b4_ = voff0 + 16384,  b5_ = voff0 + 20480,
              b6_ = voff0 + 24576,  b7_ = voff0 + 28672;
    u32x4 hd[32];
    // ---- bulk tagged load: h(t-1), 32 x dwordx4, one latency round ----
#define HLD(I, V, OFF)                                                       \
    asm volatile("global_load_dwordx4 %0, %1, %2 offset:" #OFF " sc0 sc1"    \
                 : "=v"(hd[I]) : "v"(V), "s"(hslot));
    HLD(0,b0_,0)  HLD(1,b0_,16)  HLD(2,b0_,2048)  HLD(3,b0_,2064)
    HLD(4,b1_,0)  HLD(5,b1_,16)  HLD(6,b1_,2048)  HLD(7,b1_,2064)
    HLD(8,b2_,0)  HLD(9,b2_,16)  HLD(10,b2_,2048) HLD(11,b2_,2064)
    HLD(12,b3_,0) HLD(13,b3_,16) HLD(14,b3_,2048) HLD(15,b3_,2064)
    HLD(16,b4_,0) HLD(17,b4_,16) HLD(18,b4_,2048) HLD(19,b4_,2064)
    HLD(20,b5_,0) HLD(21,b5_,16) HLD(22,b5_,2048) HLD(23,b5_,2064)
    HLD(24,b6_,0) HLD(25,b6_,16) HLD(26,b6_,2048) HLD(27,b6_,2064)
    HLD(28,b7_,0) HLD(29,b7_,16) HLD(30,b7_,2048) HLD(31,b7_,2064)
#undef HLD
    asm volatile("s_waitcnt vmcnt(0)" ::: "memory");
    // ---- validate embedded tags == t; stale-only exec-masked retry ----
    const u32 texp = (u32)t;
    for (;;) {
      u32 bad = 0;
#pragma unroll
      for (int s = 0; s < 32; ++s)
        bad |= (hd[s][0] ^ texp) | (hd[s][1] ^ texp) |
               (hd[s][2] ^ texp) | (hd[s][3] ^ texp);
      bad &= 0xFFFFu;
      if (__all(bad == 0)) break;
      __builtin_amdgcn_s_sleep(1);
#define RLD(I, V, OFF)                                                       \
      { const u32 m = ((hd[I][0]^texp)|(hd[I][1]^texp)|(hd[I][2]^texp)|      \
                       (hd[I][3]^texp)) & 0xFFFFu;                           \
        if (m) asm volatile("global_load_dwordx4 %0, %1, %2 offset:" #OFF    \
                            " sc0 sc1" : "+v"(hd[I]) : "v"(V), "s"(hslot)); }
      RLD(0,b0_,0)  RLD(1,b0_,16)  RLD(2,b0_,2048)  RLD(3,b0_,2064)
      RLD(4,b1_,0)  RLD(5,b1_,16)  RLD(6,b1_,2048)  RLD(7,b1_,2064)
      RLD(8,b2_,0)  RLD(9,b2_,16)  RLD(10,b2_,2048) RLD(11,b2_,2064)
      RLD(12,b3_,0) RLD(13,b3_,16) RLD(14,b3_,2048) RLD(15,b3_,2064)
      RLD(16,b4_,0) RLD(17,b4_,16) RLD(18,b4_,2048) RLD(19,b4_,2064)
      RLD(20,b5_,0) RLD(21,b5_,16) RLD(22,b5_,2048) RLD(23,b5_,2064)
      RLD(24,b6_,0) RLD(25,b6_,16) RLD(26,b6_,2048) RLD(27,b6_,2064)
      RLD(28,b7_,0) RLD(29,b7_,16) RLD(30,b7_,2048) RLD(31,b7_,2064)
#undef RLD
      asm volatile("s_waitcnt vmcnt(0)" ::: "memory");
    }
    __builtin_amdgcn_sched_barrier(0);

    // ---- extract bf16 (hi16) + MFMA (4 gates) over 16 K-subtiles ----
    f32x4 a0 = {0.f, 0.f, 0.f, 0.f}, a1 = a0, a2 = a0, a3 = a0;
#pragma unroll
    for (int ks = 0; ks < 16; ++ks) {
      const u32x4 d0 = hd[2 * ks], d1 = hd[2 * ks + 1];
      union { u32 w[4]; bf16x8 v; } f;
      f.w[0] = (d0[0] >> 16) | (d0[1] & 0xFFFF0000u);
      f.w[1] = (d0[2] >> 16) | (d0[3] & 0xFFFF0000u);
      f.w[2] = (d1[0] >> 16) | (d1[1] & 0xFFFF0000u);
      f.w[3] = (d1[2] >> 16) | (d1[3] & 0xFFFF0000u);
      const int k = (wave << 9) + (ks << 5) + ak;
      a0 = __builtin_amdgcn_mfma_f32_16x16x32_bf16(f.v, wread(wlds, am, k),      a0, 0, 0, 0);
      a1 = __builtin_amdgcn_mfma_f32_16x16x32_bf16(f.v, wread(wlds, am + 16, k), a1, 0, 0, 0);
      a2 = __builtin_amdgcn_mfma_f32_16x16x32_bf16(f.v, wf[0][ks], a2, 0, 0, 0);
      a3 = __builtin_amdgcn_mfma_f32_16x16x32_bf16(f.v, wf[1][ks], a3, 0, 0, 0);
    }
    {  // D: row=(lane>>4)*4+r = batch, col=lane&15 = col-within-gate
      float* rw = red + (wave << 10);
      const int mrow = (lane >> 4) << 2;
#pragma unroll
      for (int r = 0; r < 4; ++r) {
        rw[(mrow + r) * 64 + am]      = a0[r];
        rw[(mrow + r) * 64 + 16 + am] = a1[r];
        rw[(mrow + r) * 64 + 32 + am] = a2[r];
        rw[(mrow + r) * 64 + 48 + am] = a3[r];
      }
    }
    // B1: LDS-only barrier (publish/out/xg stores may stay in flight)
    asm volatile("s_waitcnt lgkmcnt(0)\n\ts_barrier" ::: "memory");
    // ---- gates: thread (bb,jj); sum 4 wave partials + xg ----
    float g4[4];
#pragma unroll
    for (int g = 0; g < 4; ++g) {
      const int n = (bb << 6) + (g << 4) + jj;
      g4[g] = red[n] + red[1024 + n] + red[2048 + n] + red[3072 + n] + bf2f(xv[g]);
    }
    const float gi = sigm(g4[0]);
    const float gf = sigm(g4[1]);
    const float gg = tanh_fast(g4[2]);
    const float go = sigm(g4[3]);
    c = gf * c + gi * gg;
    const float h = go * tanh_fast(c);
    // ---- publish h(t): ONE tagged u32 write-through store; no drain ----
    {
      const u32 hw = ((u32)f2bf(h) << 16) | (u32)(t + 1);
      __hip_atomic_store(hbuf + (par << 15) + (blockIdx.x << 8) + tid, hw,
                         __ATOMIC_RELAXED, __HIP_MEMORY_SCOPE_AGENT);
    }
    // out store + next xg prefetch (fire-and-forget / auto-waited on use)
    out[(((long)(bb << 10) + t) << 11) + j0 + jj] = h;
    {
      const int tn = (t + 1 < 1024) ? t + 1 : 0;
#pragma unroll
      for (int g = 0; g < 4; ++g)
        xv[g] = xg[((long)((bb << 10) + tn)) * 8192 + (g << 11) + j0 + jj];
    }
    // B2: red WAR, LDS-only barrier (stores still in flight)
    asm volatile("s_waitcnt lgkmcnt(0)\n\ts_barrier" ::: "memory");
  }
}

// ------------------------------- launcher ----------------------------------
extern "C" void kernel_launch(void* const* d_in, const int* in_sizes, int n_in,
                              void* d_out, int out_size, void* d_ws, size_t ws_size,
                              hipStream_t stream) {
  const float* feats = (const float*)d_in[0];
  const float* Wq = (const float*)d_in[1];
  const float* bq = (const float*)d_in[2];
  const float* Wk = (const float*)d_in[3];
  const float* bk = (const float*)d_in[4];
  const float* Wv = (const float*)d_in[5];
  const float* bv = (const float*)d_in[6];
  const float* Wih = (const float*)d_in[7];
  const float* Whh = (const float*)d_in[8];
  const float* bih = (const float*)d_in[9];
  const float* bhh = (const float*)d_in[10];
  float* out = (float*)d_out;
  char* ws = (char*)d_ws;

  // workspace layout (bytes); peak ~408 MB with region reuse
  u16* feats16 = (u16*)(ws + 0L);
  u16* q16     = (u16*)(ws + 67108864L);
  u16* k16     = (u16*)(ws + 134217728L);
  u16* v16     = (u16*)(ws + 201326592L);
  u16* vT16    = feats16;                   // reuse after QKV
  u16* P16     = q16;                       // reuse after scores GEMM
  u16* xg16    = (u16*)(ws + 0L);           // reuse [0,256MB) after PV
  u16* nf16    = (u16*)(ws + 268435456L);
  u16* wq16    = (u16*)(ws + 335544320L);
  u16* wk16    = (u16*)(ws + 343932928L);
  u16* wv16    = (u16*)(ws + 352321536L);
  u16* wih16   = (u16*)(ws + 360710144L);
  u16* whh16   = (u16*)(ws + 394264576L);
  float* biassum = (float*)(ws + 427819008L);
  u32* hbuf    = (u32*)(ws + 427851776L);   // [2][128][16][16] u32 tagged h
  float* scoresf = (float*)d_out;           // d_out as scratch; LSTM overwrites

  // bf16 conversions
  k_cvt<<<16384, 256, 0, stream>>>(feats, feats16, 33554432L);
  k_cvt<<<2048, 256, 0, stream>>>(Wq, wq16, 4194304L);
  k_cvt<<<2048, 256, 0, stream>>>(Wk, wk16, 4194304L);
  k_cvt<<<2048, 256, 0, stream>>>(Wv, wv16, 4194304L);
  k_cvt<<<8192, 256, 0, stream>>>(Wih, wih16, 16777216L);
  k_cvt<<<8192, 256, 0, stream>>>(Whh, whh16, 16777216L);
  k_addb<<<32, 256, 0, stream>>>(bih, bhh, biassum, 8192);

  // q,k,v = feats @ W^T + b
  k_gemm_nt<1><<<dim3(16, 128, 1), 256, 0, stream>>>(feats16, wq16, q16, bq, 1.f, 16384, 2048, 2048, 0, 0, 0);
  k_gemm_nt<1><<<dim3(16, 128, 1), 256, 0, stream>>>(feats16, wk16, k16, bk, 1.f, 16384, 2048, 2048, 0, 0, 0);
  k_gemm_nt<1><<<dim3(16, 128, 1), 256, 0, stream>>>(feats16, wv16, v16, bv, 1.f, 16384, 2048, 2048, 0, 0, 0);
  // scores = q k^T / sqrt(2048)   (batched, fp32 into d_out scratch)
  k_gemm_nt<0><<<dim3(8, 8, 16), 256, 0, stream>>>(q16, k16, scoresf, nullptr, 0.022097086912079608f,
                                                   1024, 1024, 2048, 2097152, 2097152, 1048576);
  k_softmax<<<16384, 256, 0, stream>>>(scoresf, P16);
  k_transpose<<<dim3(32, 16, 16), 256, 0, stream>>>(v16, vT16);
  // new_feats = P @ V  (via V^T, batched)
  k_gemm_nt<1><<<dim3(16, 8, 16), 256, 0, stream>>>(P16, vT16, nf16, nullptr, 1.f,
                                                    1024, 2048, 1024, 1048576, 2097152, 2097152);
  // xg = new_feats @ W_ih^T + (b_ih + b_hh)
  k_gemm_nt<1><<<dim3(64, 128, 1), 256, 0, stream>>>(nf16, wih16, xg16, biassum, 1.f, 16384, 8192, 2048, 0, 0, 0);

  // LSTM recurrence (persistent kernel, tagged-data protocol)
  hipMemsetAsync(ws + 427851776L, 0, 262144, stream);  // hbuf: h=0, tag=0 (t=0 passes)
  const int dynlds = 131072 + 16384;  // W gates 0,1 + red
  (void)hipFuncSetAttribute((const void*)k_lstm, hipFuncAttributeMaxDynamicSharedMemorySize, dynlds);
  void* kargs[] = {(void*)&xg16, (void*)&whh16, (void*)&hbuf, (void*)&out};
  hipError_t ce = hipLaunchCooperativeKernel((const void*)k_lstm, dim3(128), dim3(256),
                                             kargs, dynlds, stream);
  if (ce != hipSuccess) {
    // Silent coop-launch rejection (rounds 3/6) -> plain launch fallback:
    // 128 blocks at 1 block/CU on an idle 256-CU GPU are co-resident.
    k_lstm<<<dim3(128), dim3(256), dynlds, stream>>>(xg16, whh16, hbuf, out);
  }
}

// Round 13
// 6778.866 us; speedup vs baseline: 1.2658x; 1.2658x over previous
//
#include <hip/hip_runtime.h>

// ---------------------------------------------------------------------------
// SelfAttention (QKV -> softmax(QK^T/sqrt(D)) V) -> LSTM(1024 steps)
// B=16, S=1024, D=H=2048.  All heavy math in bf16 MFMA, fp32 accumulate.
// ---------------------------------------------------------------------------

typedef unsigned short u16;
typedef unsigned int u32;
typedef unsigned long long u64;
typedef __attribute__((ext_vector_type(8))) __bf16 bf16x8;
typedef __attribute__((ext_vector_type(8))) unsigned short u16x8;
typedef __attribute__((ext_vector_type(4))) float f32x4;
typedef __attribute__((ext_vector_type(4))) unsigned int u32x4;

#define DEV static __device__ __forceinline__

DEV u16 f2bf(float f) {  // RTNE float->bf16 (finite inputs)
  union { float f; unsigned u; } x; x.f = f;
  return (u16)((x.u + 0x7FFFu + ((x.u >> 16) & 1u)) >> 16);
}
DEV float bf2f(u16 h) {
  union { unsigned u; float f; } x; x.u = (unsigned)h << 16;
  return x.f;
}
DEV void gload_lds16(const void* g, void* l) {
  __builtin_amdgcn_global_load_lds(
      (const __attribute__((address_space(1))) unsigned int*)g,
      (__attribute__((address_space(3))) unsigned int*)l, 16, 0, 0);
}

// -------------------------- fp32 -> bf16 convert ---------------------------
__global__ __launch_bounds__(256) void k_cvt(const float* __restrict__ in,
                                             u16* __restrict__ out, long n) {
  long i = (((long)blockIdx.x << 8) | threadIdx.x) << 3;
  if (i >= n) return;
  float4 f0 = *(const float4*)(in + i);
  float4 f1 = *(const float4*)(in + i + 4);
  u16x8 p;
  p[0] = f2bf(f0.x); p[1] = f2bf(f0.y); p[2] = f2bf(f0.z); p[3] = f2bf(f0.w);
  p[4] = f2bf(f1.x); p[5] = f2bf(f1.y); p[6] = f2bf(f1.z); p[7] = f2bf(f1.w);
  *(u16x8*)(out + i) = p;
}

__global__ __launch_bounds__(256) void k_addb(const float* __restrict__ a,
                                              const float* __restrict__ b,
                                              float* __restrict__ o, int n) {
  int i = blockIdx.x * 256 + threadIdx.x;
  if (i < n) o[i] = a[i] + b[i];
}

// ------------------------------- NT GEMM (128² m97) ------------------------
// Used for scores (fp32 out, scaled) and PV.  Proven rounds 1-12.
template<int OBF>
__global__ __launch_bounds__(256) void k_gemm_nt(
    const u16* __restrict__ A, const u16* __restrict__ B, void* __restrict__ Cv,
    const float* __restrict__ bias, float scale, int M, int N, int K,
    long sA, long sB, long sC) {
  __shared__ __attribute__((aligned(16))) u16 As[4096];  // [128][32]
  __shared__ __attribute__((aligned(16))) u16 Bs[4096];
  const int tid = threadIdx.x;
  const int lane = tid & 63;
  const int wm = ((tid >> 7) & 1) * 64;   // wave row
  const int wn = ((tid >> 6) & 1) * 64;   // wave col
  const int gx = gridDim.x;
  int lin = blockIdx.y * gx + blockIdx.x;
  const int nwg = gx * gridDim.y;
  if ((nwg & 7) == 0) lin = (lin & 7) * (nwg >> 3) + (lin >> 3);
  const long bm = (long)(lin / gx) << 7;
  const long bn = (long)(lin % gx) << 7;
  const u16* Ab = A + (long)blockIdx.z * sA;
  const u16* Bb = B + (long)blockIdx.z * sB;
  const int srow = tid >> 2, scol = (tid & 3) << 3;
  const u16* ga0 = Ab + (bm + srow) * (long)K + scol;
  const u16* gb0 = Bb + (bn + srow) * (long)K + scol;
  const long k64 = (long)K << 6;          // 64 rows worth of elements
  char* lA = (char*)As + tid * 16;
  char* lB = (char*)Bs + tid * 16;
  f32x4 acc[4][4] = {};
  const int fr = lane & 15, fk = (lane >> 4) << 3;
  for (int kt = 0; kt < K; kt += 32) {
    gload_lds16(ga0 + kt, lA);
    gload_lds16(ga0 + k64 + kt, lA + 4096);
    gload_lds16(gb0 + kt, lB);
    gload_lds16(gb0 + k64 + kt, lB + 4096);
    __syncthreads();
    bf16x8 av[4], bv[4];
#pragma unroll
    for (int x = 0; x < 4; ++x) {
      av[x] = *(const bf16x8*)&As[(wm + x * 16 + fr) * 32 + fk];
      bv[x] = *(const bf16x8*)&Bs[(wn + x * 16 + fr) * 32 + fk];
    }
#pragma unroll
    for (int i = 0; i < 4; ++i)
#pragma unroll
      for (int j = 0; j < 4; ++j)
        acc[i][j] = __builtin_amdgcn_mfma_f32_16x16x32_bf16(av[i], bv[j], acc[i][j], 0, 0, 0);
    __syncthreads();
  }
  const long cb = (long)blockIdx.z * sC;
#pragma unroll
  for (int j = 0; j < 4; ++j) {
    const long col = bn + wn + j * 16 + fr;
    const float bb = bias ? bias[col] : 0.f;
#pragma unroll
    for (int i = 0; i < 4; ++i) {
      const long r0 = bm + wm + i * 16 + ((lane >> 4) << 2);
#pragma unroll
      for (int r = 0; r < 4; ++r) {
        const float v = acc[i][j][r] * scale + bb;
        const long off = cb + (r0 + r) * (long)N + col;
        if (OBF) ((u16*)Cv)[off] = f2bf(v);
        else     ((float*)Cv)[off] = v;
      }
    }
  }
}

// ----------------------- 256² deep-pipelined NT GEMM -----------------------
// BM=BN=256, BK=32, 512 threads (8 waves, 2Mx4N), per-wave 128x64 output.
// LDS: 4 slots x (A 16KB + B 16KB) = 128KB, st_16x32 XOR swizzle
// (byte ^= ((byte>>9)&1)<<5; both-sides: inverse-swizzled global SOURCE for
// the linear global_load_lds dest + swizzled ds_read addresses).
// Schedule: 3-tile-deep prefetch; per K-step: stage(kt+3) -> vmcnt(12) ->
// s_barrier -> 12 ds_read_b128 -> lgkmcnt(0) -> s_barrier -> 32 MFMA
// (setprio-wrapped).  vmcnt never drains to 0 in the main loop (tail 8/4/0).
// Slot-overwrite race: slot kt&3 is restaged at iter kt+1, i.e. after
// bar2(kt) where every wave's reads of that slot have executed.
__global__ __launch_bounds__(512, 2) void k_gemm256(
    const u16* __restrict__ A, const u16* __restrict__ B,
    u16* __restrict__ C, const float* __restrict__ bias, int N, int K) {
  extern __shared__ u16 lds[];
  u16* As = lds;                    // [4][8192]
  u16* Bs = lds + 32768;            // [4][8192]
  const int tid = threadIdx.x;
  const int lane = tid & 63, wid = tid >> 6;
  const int wm = (wid >> 2) & 1, wn = wid & 3;
  const int gx = gridDim.x;
  int lin = blockIdx.y * gx + blockIdx.x;
  const int nwg = gx * gridDim.y;
  if ((nwg & 7) == 0) lin = (lin & 7) * (nwg >> 3) + (lin >> 3);
  const long bm = (long)(lin / gx) << 8;
  const long bn = (long)(lin % gx) << 8;
  const int NK = K >> 5;

  // staging: thread chunk p in {0,1}: physical LDS byte q = p*8192 + tid*16,
  // logical q' = q ^ ((q>>9&1)<<5) -> (row = q'>>6, colbyte = q'&63)
  u32 srow[2], scolb[2];
#pragma unroll
  for (int p = 0; p < 2; ++p) {
    const u32 q = (u32)(p * 8192 + tid * 16);
    const u32 qp = q ^ (((q >> 9) & 1u) << 5);
    srow[p] = qp >> 6; scolb[p] = qp & 63u;
  }
#define STAGE256(S, KT)                                                      \
  {                                                                          \
    _Pragma("unroll")                                                        \
    for (int p = 0; p < 2; ++p) {                                            \
      const u32 q = (u32)(p * 8192 + tid * 16);                              \
      gload_lds16(A + (bm + srow[p]) * (long)K + (KT) * 32 + (scolb[p] >> 1),\
                  (char*)As + (S) * 16384 + q);                              \
      gload_lds16(B + (bn + srow[p]) * (long)K + (KT) * 32 + (scolb[p] >> 1),\
                  (char*)Bs + (S) * 16384 + q);                              \
    }                                                                        \
  }

  // fragment read byte offsets (within a 16KB slot), swizzled
  const int fr = lane & 15, fkb = ((lane >> 4) << 3) << 1;
  u32 abyte[8], bbyte[4];
#pragma unroll
  for (int mi = 0; mi < 8; ++mi) {
    const u32 row = (u32)(wm * 128 + mi * 16 + fr);
    abyte[mi] = (row * 64 + (u32)fkb) ^ ((row & 8u) ? 32u : 0u);
  }
#pragma unroll
  for (int ni = 0; ni < 4; ++ni) {
    const u32 row = (u32)(wn * 64 + ni * 16 + fr);
    bbyte[ni] = (row * 64 + (u32)fkb) ^ ((row & 8u) ? 32u : 0u);
  }

  f32x4 acc[8][4] = {};
#define COMPUTE256(SLOT)                                                     \
  {                                                                          \
    const char* sa = (const char*)As + (SLOT) * 16384;                       \
    const char* sb = (const char*)Bs + (SLOT) * 16384;                       \
    bf16x8 av[8], bv[4];                                                     \
    _Pragma("unroll")                                                        \
    for (int mi = 0; mi < 8; ++mi) av[mi] = *(const bf16x8*)(sa + abyte[mi]);\
    _Pragma("unroll")                                                        \
    for (int ni = 0; ni < 4; ++ni) bv[ni] = *(const bf16x8*)(sb + bbyte[ni]);\
    asm volatile("s_waitcnt lgkmcnt(0)" ::: "memory");                       \
    __builtin_amdgcn_s_barrier();                                            \
    __builtin_amdgcn_s_setprio(1);                                           \
    _Pragma("unroll")                                                        \
    for (int mi = 0; mi < 8; ++mi)                                           \
      _Pragma("unroll")                                                      \
      for (int ni = 0; ni < 4; ++ni)                                         \
        acc[mi][ni] = __builtin_amdgcn_mfma_f32_16x16x32_bf16(               \
            av[mi], bv[ni], acc[mi][ni], 0, 0, 0);                           \
    __builtin_amdgcn_s_setprio(0);                                           \
  }

  // prologue: 3 tiles in flight
  STAGE256(0, 0)
  STAGE256(1, 1)
  STAGE256(2, 2)
  int kt = 0;
  for (; kt < NK - 3; ++kt) {
    STAGE256((kt + 3) & 3, kt + 3)
    asm volatile("s_waitcnt vmcnt(12)" ::: "memory");
    __builtin_amdgcn_s_barrier();
    COMPUTE256(kt & 3)
  }
  asm volatile("s_waitcnt vmcnt(8)" ::: "memory");
  __builtin_amdgcn_s_barrier();
  COMPUTE256(kt & 3) ++kt;
  asm volatile("s_waitcnt vmcnt(4)" ::: "memory");
  __builtin_amdgcn_s_barrier();
  COMPUTE256(kt & 3) ++kt;
  asm volatile("s_waitcnt vmcnt(0)" ::: "memory");
  __builtin_amdgcn_s_barrier();
  COMPUTE256(kt & 3)
#undef STAGE256
#undef COMPUTE256

  // epilogue: bias + bf16 store
#pragma unroll
  for (int ni = 0; ni < 4; ++ni) {
    const long col = bn + wn * 64 + ni * 16 + fr;
    const float bb = bias ? bias[col] : 0.f;
#pragma unroll
    for (int mi = 0; mi < 8; ++mi) {
      const long r0 = bm + wm * 128 + mi * 16 + ((lane >> 4) << 2);
#pragma unroll
      for (int r = 0; r < 4; ++r)
        C[(r0 + r) * (long)N + col] = f2bf(acc[mi][ni][r] + bb);
    }
  }
}

// ------------------------------ row softmax --------------------------------
__global__ __launch_bounds__(256) void k_softmax(const float* __restrict__ S,
                                                 u16* __restrict__ P) {
  __shared__ float red[8];
  const long row = blockIdx.x;
  const float* sr = S + (row << 10);
  const int t = threadIdx.x, lane = t & 63, w = t >> 6;
  float v0 = sr[t], v1 = sr[t + 256], v2 = sr[t + 512], v3 = sr[t + 768];
  float m = fmaxf(fmaxf(v0, v1), fmaxf(v2, v3));
#pragma unroll
  for (int o = 32; o; o >>= 1) m = fmaxf(m, __shfl_xor(m, o));
  if (lane == 0) red[w] = m;
  __syncthreads();
  m = fmaxf(fmaxf(red[0], red[1]), fmaxf(red[2], red[3]));
  v0 = __expf(v0 - m); v1 = __expf(v1 - m); v2 = __expf(v2 - m); v3 = __expf(v3 - m);
  float s = v0 + v1 + v2 + v3;
#pragma unroll
  for (int o = 32; o; o >>= 1) s += __shfl_xor(s, o);
  if (lane == 0) red[4 + w] = s;
  __syncthreads();
  s = red[4] + red[5] + red[6] + red[7];
  const float rs = 1.f / s;
  u16* pr = P + (row << 10);
  pr[t] = f2bf(v0 * rs); pr[t + 256] = f2bf(v1 * rs);
  pr[t + 512] = f2bf(v2 * rs); pr[t + 768] = f2bf(v3 * rs);
}

// ------------------------- V transpose (per batch) -------------------------
__global__ __launch_bounds__(256) void k_transpose(const u16* __restrict__ V,
                                                   u16* __restrict__ VT) {
  __shared__ __attribute__((aligned(16))) u16 tile[64][80];
  const long b = blockIdx.z;
  const long t0 = (long)blockIdx.y << 6, d0 = (long)blockIdx.x << 6;
  const int r = threadIdx.x >> 3, c8 = (threadIdx.x & 7) << 3;
  const u16* src = V + ((b << 10) + t0) * 2048 + d0;
#pragma unroll
  for (int p = 0; p < 2; ++p) {
    const int rr = r + p * 32;
    *(u16x8*)&tile[rr][c8] = *(const u16x8*)(src + (long)rr * 2048 + c8);
  }
  __syncthreads();
  u16* dst = VT + ((b << 11) + d0) * 1024 + t0;
#pragma unroll
  for (int p = 0; p < 2; ++p) {
    const int dr = r + p * 32;
    u16x8 pk;
#pragma unroll
    for (int q = 0; q < 8; ++q) pk[q] = tile[c8 + q][dr];
    *(u16x8*)(dst + (long)dr * 1024 + c8) = pk;
  }
}

// ------------------------------ LSTM recurrence ----------------------------
// ROUND-9 VERBATIM (best measured: 5.17 ms).  128 blocks x 256 threads.
DEV bf16x8 wread(const char* wlds, int nrow, int k) {
  int byte = (nrow << 12) + (k << 1);
  byte ^= (nrow & 7) << 4;
  return *(const bf16x8*)(wlds + byte);
}
DEV float sigm(float x) { return 1.f / (1.f + __expf(-x)); }
DEV float tanh_fast(float x) { return 1.f - 2.f / (1.f + __expf(2.f * x)); }

__global__ __launch_bounds__(256, 1) void k_lstm(
    const u16* __restrict__ xg, const u16* __restrict__ whh,
    u16* __restrict__ hbuf, float* __restrict__ out,
    unsigned* __restrict__ flg) {
  extern __shared__ char smem[];
  char* wlds = smem;                       // 32 x 2048 bf16 = 131072 B (gates 0,1)
  float* red = (float*)(smem + 131072);    // [4 waves][16 batch x 64 gcol] = 16 KB
  const int tid = threadIdx.x, lane = tid & 63, wave = tid >> 6;
  const int j0 = blockIdx.x << 4;          // 16 columns per block
  const int am = lane & 15, ak = (lane >> 4) << 3;
  const int bb = tid >> 4, jj = tid & 15;  // gate-stage cell (all 256 threads)

  for (int it = 0; it < 32; ++it) {
    const long grow = ((long)(it >> 4) << 11) + j0 + (it & 15);
    const u16* src = whh + grow * 2048 + (tid << 3);
    int byte = (it << 12) + (tid << 4);
    byte ^= (it & 7) << 4;
    *(bf16x8*)(wlds + byte) = *(const bf16x8*)src;
  }
  bf16x8 wf[2][16];
#pragma unroll
  for (int g2 = 0; g2 < 2; ++g2)
#pragma unroll
    for (int ks = 0; ks < 16; ++ks)
      wf[g2][ks] = *(const bf16x8*)(whh + ((long)((2 + g2) << 11) + j0 + am) * 2048 +
                                    (wave << 9) + (ks << 5) + ak);
  __syncthreads();

  float c = 0.f;
  unsigned* const myflag = flg + (((wave << 5) + (lane & 31)) << 2);  // 16B stride
  u16 xv[4];
#pragma unroll
  for (int g = 0; g < 4; ++g)
    xv[g] = xg[((long)bb << 10) * 8192 + (g << 11) + j0 + jj];

  for (int t = 0; t < 1024; ++t) {
    const int par = t & 1;
    unsigned dep = 0;
    if (t) {
      const unsigned tgt = (unsigned)t;
      unsigned v = tgt;
      for (;;) {
        if (lane < 32)
          v = __hip_atomic_load(myflag, __ATOMIC_RELAXED, __HIP_MEMORY_SCOPE_AGENT);
        if (__all(v >= tgt)) break;
        __builtin_amdgcn_s_sleep(1);
      }
      dep = v >> 20;
    }
    asm volatile("" : "+v"(dep)::);

    const u16* hbase = hbuf + ((par ^ 1) << 15);
    const u32 voff = ((am << 11) + (wave << 9) + ak + dep) << 1;
    u32x4 hd[16];
#define HLD(I, OFF)                                                          \
    asm volatile("global_load_dwordx4 %0, %1, %2 offset:" #OFF " sc0 sc1"    \
                 : "=v"(hd[I]) : "v"(voff), "s"(hbase));
    HLD(0, 0)    HLD(1, 64)   HLD(2, 128)  HLD(3, 192)
    HLD(4, 256)  HLD(5, 320)  HLD(6, 384)  HLD(7, 448)
    HLD(8, 512)  HLD(9, 576)  HLD(10, 640) HLD(11, 704)
    HLD(12, 768) HLD(13, 832) HLD(14, 896) HLD(15, 960)
#undef HLD
    asm volatile("s_waitcnt vmcnt(0)" ::: "memory");
    __builtin_amdgcn_sched_barrier(0);

    f32x4 a0 = {0.f, 0.f, 0.f, 0.f}, a1 = a0, a2 = a0, a3 = a0;
#pragma unroll
    for (int ks = 0; ks < 16; ++ks) {
      union { u32x4 d; bf16x8 v; } u;
      u.d = hd[ks];
      const int k = (wave << 9) + (ks << 5) + ak;
      a0 = __builtin_amdgcn_mfma_f32_16x16x32_bf16(u.v, wread(wlds, am, k),      a0, 0, 0, 0);
      a1 = __builtin_amdgcn_mfma_f32_16x16x32_bf16(u.v, wread(wlds, am + 16, k), a1, 0, 0, 0);
      a2 = __builtin_amdgcn_mfma_f32_16x16x32_bf16(u.v, wf[0][ks], a2, 0, 0, 0);
      a3 = __builtin_amdgcn_mfma_f32_16x16x32_bf16(u.v, wf[1][ks], a3, 0, 0, 0);
    }
    {
      float* rw = red + (wave << 10);
      const int mrow = (lane >> 4) << 2;
#pragma unroll
      for (int r = 0; r < 4; ++r) {
        rw[(mrow + r) * 64 + am]      = a0[r];
        rw[(mrow + r) * 64 + 16 + am] = a1[r];
        rw[(mrow + r) * 64 + 32 + am] = a2[r];
        rw[(mrow + r) * 64 + 48 + am] = a3[r];
      }
    }
    __syncthreads();
    float g4[4];
#pragma unroll
    for (int g = 0; g < 4; ++g) {
      const int n = (bb << 6) + (g << 4) + jj;
      g4[g] = red[n] + red[1024 + n] + red[2048 + n] + red[3072 + n] + bf2f(xv[g]);
    }
    const float gi = sigm(g4[0]);
    const float gf = sigm(g4[1]);
    const float gg = tanh_fast(g4[2]);
    const float go = sigm(g4[3]);
    c = gf * c + gi * gg;
    const float h = go * tanh_fast(c);
    {
      const unsigned hb = (unsigned)f2bf(h);
      const unsigned p1 = (unsigned)__shfl_xor((int)hb, 1);
      const unsigned w2 = (hb & 0xFFFFu) | (p1 << 16);
      const unsigned p2 = (unsigned)__shfl_xor((int)w2, 2);
      if ((jj & 3) == 0) {
        const u64 hw = (u64)w2 | ((u64)p2 << 32);
        u16* dst = hbuf + (par << 15) + (bb << 11) + j0 + jj;
        __hip_atomic_store((u64*)dst, hw, __ATOMIC_RELAXED, __HIP_MEMORY_SCOPE_AGENT);
      }
    }
    asm volatile("s_waitcnt vmcnt(0)" ::: "memory");
    __syncthreads();
    if (tid == 0)
      __hip_atomic_store(flg + (blockIdx.x << 2), (unsigned)(t + 1),
                         __ATOMIC_RELAXED, __HIP_MEMORY_SCOPE_AGENT);
    out[(((long)(bb << 10) + t) << 11) + j0 + jj] = h;
    {
      const int tn = (t + 1 < 1024) ? t + 1 : 0;
#pragma unroll
      for (int g = 0; g < 4; ++g)
        xv[g] = xg[((long)((bb << 10) + tn)) * 8192 + (g << 11) + j0 + jj];
    }
    asm volatile("" ::: "memory");
  }
}

// ------------------------------- launcher ----------------------------------
extern "C" void kernel_launch(void* const* d_in, const int* in_sizes, int n_in,
                              void* d_out, int out_size, void* d_ws, size_t ws_size,
                              hipStream_t stream) {
  const float* feats = (const float*)d_in[0];
  const float* Wq = (const float*)d_in[1];
  const float* bq = (const float*)d_in[2];
  const float* Wk = (const float*)d_in[3];
  const float* bk = (const float*)d_in[4];
  const float* Wv = (const float*)d_in[5];
  const float* bv = (const float*)d_in[6];
  const float* Wih = (const float*)d_in[7];
  const float* Whh = (const float*)d_in[8];
  const float* bih = (const float*)d_in[9];
  const float* bhh = (const float*)d_in[10];
  float* out = (float*)d_out;
  char* ws = (char*)d_ws;

  u16* feats16 = (u16*)(ws + 0L);
  u16* q16     = (u16*)(ws + 67108864L);
  u16* k16     = (u16*)(ws + 134217728L);
  u16* v16     = (u16*)(ws + 201326592L);
  u16* vT16    = feats16;                   // reuse after QKV
  u16* P16     = q16;                       // reuse after scores GEMM
  u16* xg16    = (u16*)(ws + 0L);           // reuse [0,256MB) after PV
  u16* nf16    = (u16*)(ws + 268435456L);
  u16* wq16    = (u16*)(ws + 335544320L);
  u16* wk16    = (u16*)(ws + 343932928L);
  u16* wv16    = (u16*)(ws + 352321536L);
  u16* wih16   = (u16*)(ws + 360710144L);
  u16* whh16   = (u16*)(ws + 394264576L);
  float* biassum = (float*)(ws + 427819008L);
  u16* hbuf    = (u16*)(ws + 427851776L);   // [2][16][2048] bf16
  unsigned* flg = (unsigned*)(ws + 427982848L);  // 128 x 16B flag slots
  float* scoresf = (float*)d_out;           // d_out as scratch; LSTM overwrites

  k_cvt<<<16384, 256, 0, stream>>>(feats, feats16, 33554432L);
  k_cvt<<<2048, 256, 0, stream>>>(Wq, wq16, 4194304L);
  k_cvt<<<2048, 256, 0, stream>>>(Wk, wk16, 4194304L);
  k_cvt<<<2048, 256, 0, stream>>>(Wv, wv16, 4194304L);
  k_cvt<<<8192, 256, 0, stream>>>(Wih, wih16, 16777216L);
  k_cvt<<<8192, 256, 0, stream>>>(Whh, whh16, 16777216L);
  k_addb<<<32, 256, 0, stream>>>(bih, bhh, biassum, 8192);

  // q,k,v = feats @ W^T + b   (256² deep-pipelined kernel, 128KB dyn LDS)
  (void)hipFuncSetAttribute((const void*)k_gemm256, hipFuncAttributeMaxDynamicSharedMemorySize, 131072);
  k_gemm256<<<dim3(8, 64), 512, 131072, stream>>>(feats16, wq16, q16, bq, 2048, 2048);
  k_gemm256<<<dim3(8, 64), 512, 131072, stream>>>(feats16, wk16, k16, bk, 2048, 2048);
  k_gemm256<<<dim3(8, 64), 512, 131072, stream>>>(feats16, wv16, v16, bv, 2048, 2048);
  // scores = q k^T / sqrt(2048)   (batched, fp32 into d_out scratch)
  k_gemm_nt<0><<<dim3(8, 8, 16), 256, 0, stream>>>(q16, k16, scoresf, nullptr, 0.022097086912079608f,
                                                   1024, 1024, 2048, 2097152, 2097152, 1048576);
  k_softmax<<<16384, 256, 0, stream>>>(scoresf, P16);
  k_transpose<<<dim3(32, 16, 16), 256, 0, stream>>>(v16, vT16);
  // new_feats = P @ V  (via V^T, batched)
  k_gemm_nt<1><<<dim3(16, 8, 16), 256, 0, stream>>>(P16, vT16, nf16, nullptr, 1.f,
                                                    1024, 2048, 1024, 1048576, 2097152, 2097152);
  // xg = new_feats @ W_ih^T + (b_ih + b_hh)   (256² kernel)
  k_gemm256<<<dim3(32, 64), 512, 131072, stream>>>(nf16, wih16, xg16, biassum, 8192, 2048);

  // LSTM recurrence (persistent kernel, R9 per-wave flag sync)
  hipMemsetAsync(ws + 427851776L, 0, 131072 + 4096, stream);  // hbuf + flags
  const int dynlds = 131072 + 16384;  // W gates 0,1 + red
  (void)hipFuncSetAttribute((const void*)k_lstm, hipFuncAttributeMaxDynamicSharedMemorySize, dynlds);
  void* kargs[] = {(void*)&xg16, (void*)&whh16, (void*)&hbuf, (void*)&out, (void*)&flg};
  hipError_t ce = hipLaunchCooperativeKernel((const void*)k_lstm, dim3(128), dim3(256),
                                             kargs, dynlds, stream);
  if (ce != hipSuccess) {
    k_lstm<<<dim3(128), dim3(256), dynlds, stream>>>(xg16, whh16, hbuf, out, flg);
  }
}

// Round 14
// 6681.155 us; speedup vs baseline: 1.2843x; 1.0146x over previous
//
#include <hip/hip_runtime.h>

// ---------------------------------------------------------------------------
// SelfAttention (QKV -> softmax(QK^T/sqrt(D)) V) -> LSTM(1024 steps)
// B=16, S=1024, D=H=2048.  All heavy math in bf16 MFMA, fp32 accumulate.
// ---------------------------------------------------------------------------

typedef unsigned short u16;
typedef unsigned int u32;
typedef unsigned long long u64;
typedef __attribute__((ext_vector_type(8))) __bf16 bf16x8;
typedef __attribute__((ext_vector_type(8))) unsigned short u16x8;
typedef __attribute__((ext_vector_type(4))) float f32x4;
typedef __attribute__((ext_vector_type(4))) unsigned int u32x4;

#define DEV static __device__ __forceinline__

DEV u16 f2bf(float f) {  // RTNE float->bf16 (finite inputs)
  union { float f; unsigned u; } x; x.f = f;
  return (u16)((x.u + 0x7FFFu + ((x.u >> 16) & 1u)) >> 16);
}
DEV float bf2f(u16 h) {
  union { unsigned u; float f; } x; x.u = (unsigned)h << 16;
  return x.f;
}
DEV void gload_lds16(const void* g, void* l) {
  __builtin_amdgcn_global_load_lds(
      (const __attribute__((address_space(1))) unsigned int*)g,
      (__attribute__((address_space(3))) unsigned int*)l, 16, 0, 0);
}

// -------------------------- fp32 -> bf16 convert ---------------------------
__global__ __launch_bounds__(256) void k_cvt(const float* __restrict__ in,
                                             u16* __restrict__ out, long n) {
  long i = (((long)blockIdx.x << 8) | threadIdx.x) << 3;
  if (i >= n) return;
  float4 f0 = *(const float4*)(in + i);
  float4 f1 = *(const float4*)(in + i + 4);
  u16x8 p;
  p[0] = f2bf(f0.x); p[1] = f2bf(f0.y); p[2] = f2bf(f0.z); p[3] = f2bf(f0.w);
  p[4] = f2bf(f1.x); p[5] = f2bf(f1.y); p[6] = f2bf(f1.z); p[7] = f2bf(f1.w);
  *(u16x8*)(out + i) = p;
}

__global__ __launch_bounds__(256) void k_addb(const float* __restrict__ a,
                                              const float* __restrict__ b,
                                              float* __restrict__ o, int n) {
  int i = blockIdx.x * 256 + threadIdx.x;
  if (i < n) o[i] = a[i] + b[i];
}

// ----------------------- 256² deep-pipelined NT GEMM -----------------------
// C[m,n] = scale*sum_k A[m,k]B[n,k] + bias[n].  BM=BN=256, BK=32, 512 thr
// (8 waves 2Mx4N, 128x64/wave).  LDS 4 slots x 32KB, st_16x32 XOR swizzle
// (both-sides: inverse-swizzled global SOURCE for linear global_load_lds
// dest + swizzled ds_read).  3-tile-deep prefetch, vmcnt(12) steady state
// (never 0 in main loop; tail 8/4/0).  Batched via blockIdx.z strides.
// Slot kt&3 restaged at iter kt+1, after bar2(kt) where reads retired.
template<int OBF>
__global__ __launch_bounds__(512, 2) void k_gemm256(
    const u16* __restrict__ A, const u16* __restrict__ B, void* __restrict__ Cv,
    const float* __restrict__ bias, float scale, int N, int K,
    long sA, long sB, long sC) {
  extern __shared__ u16 lds[];
  u16* As = lds;                    // [4][8192]
  u16* Bs = lds + 32768;            // [4][8192]
  const int tid = threadIdx.x;
  const int lane = tid & 63, wid = tid >> 6;
  const int wm = (wid >> 2) & 1, wn = wid & 3;
  const int gx = gridDim.x;
  int lin = blockIdx.y * gx + blockIdx.x;
  const int nwg = gx * gridDim.y;
  if ((nwg & 7) == 0) lin = (lin & 7) * (nwg >> 3) + (lin >> 3);
  const long bm = (long)(lin / gx) << 8;
  const long bn = (long)(lin % gx) << 8;
  A += (long)blockIdx.z * sA;
  B += (long)blockIdx.z * sB;
  const int NK = K >> 5;

  u32 srow[2], scolb[2];
#pragma unroll
  for (int p = 0; p < 2; ++p) {
    const u32 q = (u32)(p * 8192 + tid * 16);
    const u32 qp = q ^ (((q >> 9) & 1u) << 5);
    srow[p] = qp >> 6; scolb[p] = qp & 63u;
  }
#define STAGE256(S, KT)                                                      \
  {                                                                          \
    _Pragma("unroll")                                                        \
    for (int p = 0; p < 2; ++p) {                                            \
      const u32 q = (u32)(p * 8192 + tid * 16);                              \
      gload_lds16(A + (bm + srow[p]) * (long)K + (KT) * 32 + (scolb[p] >> 1),\
                  (char*)As + (S) * 16384 + q);                              \
      gload_lds16(B + (bn + srow[p]) * (long)K + (KT) * 32 + (scolb[p] >> 1),\
                  (char*)Bs + (S) * 16384 + q);                              \
    }                                                                        \
  }

  const int fr = lane & 15, fkb = ((lane >> 4) << 3) << 1;
  u32 abyte[8], bbyte[4];
#pragma unroll
  for (int mi = 0; mi < 8; ++mi) {
    const u32 row = (u32)(wm * 128 + mi * 16 + fr);
    abyte[mi] = (row * 64 + (u32)fkb) ^ ((row & 8u) ? 32u : 0u);
  }
#pragma unroll
  for (int ni = 0; ni < 4; ++ni) {
    const u32 row = (u32)(wn * 64 + ni * 16 + fr);
    bbyte[ni] = (row * 64 + (u32)fkb) ^ ((row & 8u) ? 32u : 0u);
  }

  f32x4 acc[8][4] = {};
#define COMPUTE256(SLOT)                                                     \
  {                                                                          \
    const char* sa = (const char*)As + (SLOT) * 16384;                       \
    const char* sb = (const char*)Bs + (SLOT) * 16384;                       \
    bf16x8 av[8], bv[4];                                                     \
    _Pragma("unroll")                                                        \
    for (int mi = 0; mi < 8; ++mi) av[mi] = *(const bf16x8*)(sa + abyte[mi]);\
    _Pragma("unroll")                                                        \
    for (int ni = 0; ni < 4; ++ni) bv[ni] = *(const bf16x8*)(sb + bbyte[ni]);\
    asm volatile("s_waitcnt lgkmcnt(0)" ::: "memory");                       \
    __builtin_amdgcn_s_barrier();                                            \
    __builtin_amdgcn_s_setprio(1);                                           \
    _Pragma("unroll")                                                        \
    for (int mi = 0; mi < 8; ++mi)                                           \
      _Pragma("unroll")                                                      \
      for (int ni = 0; ni < 4; ++ni)                                         \
        acc[mi][ni] = __builtin_amdgcn_mfma_f32_16x16x32_bf16(               \
            av[mi], bv[ni], acc[mi][ni], 0, 0, 0);                           \
    __builtin_amdgcn_s_setprio(0);                                           \
  }

  STAGE256(0, 0)
  STAGE256(1, 1)
  STAGE256(2, 2)
  int kt = 0;
  for (; kt < NK - 3; ++kt) {
    STAGE256((kt + 3) & 3, kt + 3)
    asm volatile("s_waitcnt vmcnt(12)" ::: "memory");
    __builtin_amdgcn_s_barrier();
    COMPUTE256(kt & 3)
  }
  asm volatile("s_waitcnt vmcnt(8)" ::: "memory");
  __builtin_amdgcn_s_barrier();
  COMPUTE256(kt & 3) ++kt;
  asm volatile("s_waitcnt vmcnt(4)" ::: "memory");
  __builtin_amdgcn_s_barrier();
  COMPUTE256(kt & 3) ++kt;
  asm volatile("s_waitcnt vmcnt(0)" ::: "memory");
  __builtin_amdgcn_s_barrier();
  COMPUTE256(kt & 3)
#undef STAGE256
#undef COMPUTE256

  // epilogue: scale + bias + store (bf16 or fp32)
  const long cb = (long)blockIdx.z * sC;
#pragma unroll
  for (int ni = 0; ni < 4; ++ni) {
    const long col = bn + wn * 64 + ni * 16 + fr;
    const float bb = bias ? bias[col] : 0.f;
#pragma unroll
    for (int mi = 0; mi < 8; ++mi) {
      const long r0 = bm + wm * 128 + mi * 16 + ((lane >> 4) << 2);
#pragma unroll
      for (int r = 0; r < 4; ++r) {
        const float v = acc[mi][ni][r] * scale + bb;
        const long off = cb + (r0 + r) * (long)N + col;
        if (OBF) ((u16*)Cv)[off] = f2bf(v);
        else     ((float*)Cv)[off] = v;
      }
    }
  }
}

// ------------------------------ row softmax --------------------------------
__global__ __launch_bounds__(256) void k_softmax(const float* __restrict__ S,
                                                 u16* __restrict__ P) {
  __shared__ float red[8];
  const long row = blockIdx.x;
  const float* sr = S + (row << 10);
  const int t = threadIdx.x, lane = t & 63, w = t >> 6;
  float v0 = sr[t], v1 = sr[t + 256], v2 = sr[t + 512], v3 = sr[t + 768];
  float m = fmaxf(fmaxf(v0, v1), fmaxf(v2, v3));
#pragma unroll
  for (int o = 32; o; o >>= 1) m = fmaxf(m, __shfl_xor(m, o));
  if (lane == 0) red[w] = m;
  __syncthreads();
  m = fmaxf(fmaxf(red[0], red[1]), fmaxf(red[2], red[3]));
  v0 = __expf(v0 - m); v1 = __expf(v1 - m); v2 = __expf(v2 - m); v3 = __expf(v3 - m);
  float s = v0 + v1 + v2 + v3;
#pragma unroll
  for (int o = 32; o; o >>= 1) s += __shfl_xor(s, o);
  if (lane == 0) red[4 + w] = s;
  __syncthreads();
  s = red[4] + red[5] + red[6] + red[7];
  const float rs = 1.f / s;
  u16* pr = P + (row << 10);
  pr[t] = f2bf(v0 * rs); pr[t + 256] = f2bf(v1 * rs);
  pr[t + 512] = f2bf(v2 * rs); pr[t + 768] = f2bf(v3 * rs);
}

// ------------------------- V transpose (per batch) -------------------------
__global__ __launch_bounds__(256) void k_transpose(const u16* __restrict__ V,
                                                   u16* __restrict__ VT) {
  __shared__ __attribute__((aligned(16))) u16 tile[64][80];
  const long b = blockIdx.z;
  const long t0 = (long)blockIdx.y << 6, d0 = (long)blockIdx.x << 6;
  const int r = threadIdx.x >> 3, c8 = (threadIdx.x & 7) << 3;
  const u16* src = V + ((b << 10) + t0) * 2048 + d0;
#pragma unroll
  for (int p = 0; p < 2; ++p) {
    const int rr = r + p * 32;
    *(u16x8*)&tile[rr][c8] = *(const u16x8*)(src + (long)rr * 2048 + c8);
  }
  __syncthreads();
  u16* dst = VT + ((b << 11) + d0) * 1024 + t0;
#pragma unroll
  for (int p = 0; p < 2; ++p) {
    const int dr = r + p * 32;
    u16x8 pk;
#pragma unroll
    for (int q = 0; q < 8; ++q) pk[q] = tile[c8 + q][dr];
    *(u16x8*)(dst + (long)dr * 1024 + c8) = pk;
  }
}

// ------------------------------ LSTM recurrence ----------------------------
// ROUND-9 VERBATIM (best measured: 5.12 ms).  128 blocks x 256 threads.
DEV bf16x8 wread(const char* wlds, int nrow, int k) {
  int byte = (nrow << 12) + (k << 1);
  byte ^= (nrow & 7) << 4;
  return *(const bf16x8*)(wlds + byte);
}
DEV float sigm(float x) { return 1.f / (1.f + __expf(-x)); }
DEV float tanh_fast(float x) { return 1.f - 2.f / (1.f + __expf(2.f * x)); }

__global__ __launch_bounds__(256, 1) void k_lstm(
    const u16* __restrict__ xg, const u16* __restrict__ whh,
    u16* __restrict__ hbuf, float* __restrict__ out,
    unsigned* __restrict__ flg) {
  extern __shared__ char smem[];
  char* wlds = smem;                       // 32 x 2048 bf16 = 131072 B (gates 0,1)
  float* red = (float*)(smem + 131072);    // [4 waves][16 batch x 64 gcol] = 16 KB
  const int tid = threadIdx.x, lane = tid & 63, wave = tid >> 6;
  const int j0 = blockIdx.x << 4;          // 16 columns per block
  const int am = lane & 15, ak = (lane >> 4) << 3;
  const int bb = tid >> 4, jj = tid & 15;  // gate-stage cell (all 256 threads)

  for (int it = 0; it < 32; ++it) {
    const long grow = ((long)(it >> 4) << 11) + j0 + (it & 15);
    const u16* src = whh + grow * 2048 + (tid << 3);
    int byte = (it << 12) + (tid << 4);
    byte ^= (it & 7) << 4;
    *(bf16x8*)(wlds + byte) = *(const bf16x8*)src;
  }
  bf16x8 wf[2][16];
#pragma unroll
  for (int g2 = 0; g2 < 2; ++g2)
#pragma unroll
    for (int ks = 0; ks < 16; ++ks)
      wf[g2][ks] = *(const bf16x8*)(whh + ((long)((2 + g2) << 11) + j0 + am) * 2048 +
                                    (wave << 9) + (ks << 5) + ak);
  __syncthreads();

  float c = 0.f;
  unsigned* const myflag = flg + (((wave << 5) + (lane & 31)) << 2);  // 16B stride
  u16 xv[4];
#pragma unroll
  for (int g = 0; g < 4; ++g)
    xv[g] = xg[((long)bb << 10) * 8192 + (g << 11) + j0 + jj];

  for (int t = 0; t < 1024; ++t) {
    const int par = t & 1;
    unsigned dep = 0;
    if (t) {
      const unsigned tgt = (unsigned)t;
      unsigned v = tgt;
      for (;;) {
        if (lane < 32)
          v = __hip_atomic_load(myflag, __ATOMIC_RELAXED, __HIP_MEMORY_SCOPE_AGENT);
        if (__all(v >= tgt)) break;
        __builtin_amdgcn_s_sleep(1);
      }
      dep = v >> 20;
    }
    asm volatile("" : "+v"(dep)::);

    const u16* hbase = hbuf + ((par ^ 1) << 15);
    const u32 voff = ((am << 11) + (wave << 9) + ak + dep) << 1;
    u32x4 hd[16];
#define HLD(I, OFF)                                                          \
    asm volatile("global_load_dwordx4 %0, %1, %2 offset:" #OFF " sc0 sc1"    \
                 : "=v"(hd[I]) : "v"(voff), "s"(hbase));
    HLD(0, 0)    HLD(1, 64)   HLD(2, 128)  HLD(3, 192)
    HLD(4, 256)  HLD(5, 320)  HLD(6, 384)  HLD(7, 448)
    HLD(8, 512)  HLD(9, 576)  HLD(10, 640) HLD(11, 704)
    HLD(12, 768) HLD(13, 832) HLD(14, 896) HLD(15, 960)
#undef HLD
    asm volatile("s_waitcnt vmcnt(0)" ::: "memory");
    __builtin_amdgcn_sched_barrier(0);

    f32x4 a0 = {0.f, 0.f, 0.f, 0.f}, a1 = a0, a2 = a0, a3 = a0;
#pragma unroll
    for (int ks = 0; ks < 16; ++ks) {
      union { u32x4 d; bf16x8 v; } u;
      u.d = hd[ks];
      const int k = (wave << 9) + (ks << 5) + ak;
      a0 = __builtin_amdgcn_mfma_f32_16x16x32_bf16(u.v, wread(wlds, am, k),      a0, 0, 0, 0);
      a1 = __builtin_amdgcn_mfma_f32_16x16x32_bf16(u.v, wread(wlds, am + 16, k), a1, 0, 0, 0);
      a2 = __builtin_amdgcn_mfma_f32_16x16x32_bf16(u.v, wf[0][ks], a2, 0, 0, 0);
      a3 = __builtin_amdgcn_mfma_f32_16x16x32_bf16(u.v, wf[1][ks], a3, 0, 0, 0);
    }
    {
      float* rw = red + (wave << 10);
      const int mrow = (lane >> 4) << 2;
#pragma unroll
      for (int r = 0; r < 4; ++r) {
        rw[(mrow + r) * 64 + am]      = a0[r];
        rw[(mrow + r) * 64 + 16 + am] = a1[r];
        rw[(mrow + r) * 64 + 32 + am] = a2[r];
        rw[(mrow + r) * 64 + 48 + am] = a3[r];
      }
    }
    __syncthreads();
    float g4[4];
#pragma unroll
    for (int g = 0; g < 4; ++g) {
      const int n = (bb << 6) + (g << 4) + jj;
      g4[g] = red[n] + red[1024 + n] + red[2048 + n] + red[3072 + n] + bf2f(xv[g]);
    }
    const float gi = sigm(g4[0]);
    const float gf = sigm(g4[1]);
    const float gg = tanh_fast(g4[2]);
    const float go = sigm(g4[3]);
    c = gf * c + gi * gg;
    const float h = go * tanh_fast(c);
    {
      const unsigned hb = (unsigned)f2bf(h);
      const unsigned p1 = (unsigned)__shfl_xor((int)hb, 1);
      const unsigned w2 = (hb & 0xFFFFu) | (p1 << 16);
      const unsigned p2 = (unsigned)__shfl_xor((int)w2, 2);
      if ((jj & 3) == 0) {
        const u64 hw = (u64)w2 | ((u64)p2 << 32);
        u16* dst = hbuf + (par << 15) + (bb << 11) + j0 + jj;
        __hip_atomic_store((u64*)dst, hw, __ATOMIC_RELAXED, __HIP_MEMORY_SCOPE_AGENT);
      }
    }
    asm volatile("s_waitcnt vmcnt(0)" ::: "memory");
    __syncthreads();
    if (tid == 0)
      __hip_atomic_store(flg + (blockIdx.x << 2), (unsigned)(t + 1),
                         __ATOMIC_RELAXED, __HIP_MEMORY_SCOPE_AGENT);
    out[(((long)(bb << 10) + t) << 11) + j0 + jj] = h;
    {
      const int tn = (t + 1 < 1024) ? t + 1 : 0;
#pragma unroll
      for (int g = 0; g < 4; ++g)
        xv[g] = xg[((long)((bb << 10) + tn)) * 8192 + (g << 11) + j0 + jj];
    }
    asm volatile("" ::: "memory");
  }
}

// ------------------------------- launcher ----------------------------------
extern "C" void kernel_launch(void* const* d_in, const int* in_sizes, int n_in,
                              void* d_out, int out_size, void* d_ws, size_t ws_size,
                              hipStream_t stream) {
  const float* feats = (const float*)d_in[0];
  const float* Wq = (const float*)d_in[1];
  const float* bq = (const float*)d_in[2];
  const float* Wk = (const float*)d_in[3];
  const float* bk = (const float*)d_in[4];
  const float* Wv = (const float*)d_in[5];
  const float* bv = (const float*)d_in[6];
  const float* Wih = (const float*)d_in[7];
  const float* Whh = (const float*)d_in[8];
  const float* bih = (const float*)d_in[9];
  const float* bhh = (const float*)d_in[10];
  float* out = (float*)d_out;
  char* ws = (char*)d_ws;

  u16* feats16 = (u16*)(ws + 0L);
  u16* q16     = (u16*)(ws + 67108864L);
  u16* k16     = (u16*)(ws + 134217728L);
  u16* v16     = (u16*)(ws + 201326592L);
  u16* vT16    = feats16;                   // reuse after QKV
  u16* P16     = q16;                       // reuse after scores GEMM
  u16* xg16    = (u16*)(ws + 0L);           // reuse [0,256MB) after PV
  u16* nf16    = (u16*)(ws + 268435456L);
  u16* wq16    = (u16*)(ws + 335544320L);
  u16* wk16    = (u16*)(ws + 343932928L);
  u16* wv16    = (u16*)(ws + 352321536L);
  u16* wih16   = (u16*)(ws + 360710144L);
  u16* whh16   = (u16*)(ws + 394264576L);
  float* biassum = (float*)(ws + 427819008L);
  u16* hbuf    = (u16*)(ws + 427851776L);   // [2][16][2048] bf16
  unsigned* flg = (unsigned*)(ws + 427982848L);  // 128 x 16B flag slots
  float* scoresf = (float*)d_out;           // d_out as scratch; LSTM overwrites

  k_cvt<<<16384, 256, 0, stream>>>(feats, feats16, 33554432L);
  k_cvt<<<2048, 256, 0, stream>>>(Wq, wq16, 4194304L);
  k_cvt<<<2048, 256, 0, stream>>>(Wk, wk16, 4194304L);
  k_cvt<<<2048, 256, 0, stream>>>(Wv, wv16, 4194304L);
  k_cvt<<<8192, 256, 0, stream>>>(Wih, wih16, 16777216L);
  k_cvt<<<8192, 256, 0, stream>>>(Whh, whh16, 16777216L);
  k_addb<<<32, 256, 0, stream>>>(bih, bhh, biassum, 8192);

  (void)hipFuncSetAttribute((const void*)k_gemm256<1>, hipFuncAttributeMaxDynamicSharedMemorySize, 131072);
  (void)hipFuncSetAttribute((const void*)k_gemm256<0>, hipFuncAttributeMaxDynamicSharedMemorySize, 131072);
  // q,k,v = feats @ W^T + b   (256² deep-pipelined kernel, 128KB dyn LDS)
  k_gemm256<1><<<dim3(8, 64, 1), 512, 131072, stream>>>(feats16, wq16, q16, bq, 1.f, 2048, 2048, 0, 0, 0);
  k_gemm256<1><<<dim3(8, 64, 1), 512, 131072, stream>>>(feats16, wk16, k16, bk, 1.f, 2048, 2048, 0, 0, 0);
  k_gemm256<1><<<dim3(8, 64, 1), 512, 131072, stream>>>(feats16, wv16, v16, bv, 1.f, 2048, 2048, 0, 0, 0);
  // scores = q k^T / sqrt(2048)   (batched 256², fp32 into d_out scratch)
  k_gemm256<0><<<dim3(4, 4, 16), 512, 131072, stream>>>(q16, k16, scoresf, nullptr,
                                                        0.022097086912079608f, 1024, 2048,
                                                        2097152, 2097152, 1048576);
  k_softmax<<<16384, 256, 0, stream>>>(scoresf, P16);
  k_transpose<<<dim3(32, 16, 16), 256, 0, stream>>>(v16, vT16);
  // new_feats = P @ V  (via V^T, batched 256²)
  k_gemm256<1><<<dim3(8, 4, 16), 512, 131072, stream>>>(P16, vT16, nf16, nullptr, 1.f,
                                                        2048, 1024,
                                                        1048576, 2097152, 2097152);
  // xg = new_feats @ W_ih^T + (b_ih + b_hh)   (256² kernel)
  k_gemm256<1><<<dim3(32, 64, 1), 512, 131072, stream>>>(nf16, wih16, xg16, biassum, 1.f, 8192, 2048, 0, 0, 0);

  // LSTM recurrence (persistent kernel, R9 per-wave flag sync)
  hipMemsetAsync(ws + 427851776L, 0, 131072 + 4096, stream);  // hbuf + flags
  const int dynlds = 131072 + 16384;  // W gates 0,1 + red
  (void)hipFuncSetAttribute((const void*)k_lstm, hipFuncAttributeMaxDynamicSharedMemorySize, dynlds);
  void* kargs[] = {(void*)&xg16, (void*)&whh16, (void*)&hbuf, (void*)&out, (void*)&flg};
  hipError_t ce = hipLaunchCooperativeKernel((const void*)k_lstm, dim3(128), dim3(256),
                                             kargs, dynlds, stream);
  if (ce != hipSuccess) {
    k_lstm<<<dim3(128), dim3(256), dynlds, stream>>>(xg16, whh16, hbuf, out, flg);
  }
}